// Round 2
// baseline (263.385 us; speedup 1.0000x reference)
//
#include <hip/hip_runtime.h>

// Patch-embedding rearrange: (B=256, C=3, H=224, W=224) fp32 -> (B, 196, 768)
// out[b][ph*14+pw][c*256+i*16+j] = in[b][c][ph*16+i][pw*16+j]
//
// R5: persistent pipelined blocks (T3+T4-lite).
//  - 768 persistent blocks (3/CU @ 43KB LDS dbuf), grid-stride over the 7168
//    half-slab tiles -> exactly 28 tiles per CU, balanced.
//  - Per iteration: issue next tile's global_load_lds FIRST, then a COUNTED
//    s_waitcnt vmcnt(6) (drains only current tile's 3 loads; the 3 new loads
//    and the previous 3 stores stay in flight), raw s_barrier (no compiler
//    vmcnt(0) drain), ds_read+store, barrier, swap buffers.
//    -> the HBM read queue never empties across tile boundaries (the one-shot
//    R3/R4 structure drained it 28x per CU; ~900cy cold restart each time).
//  - vmcnt bookkeeping (per-wave queue order): [loads-t][stores-(t-1)][loads-(t+1)]
//    steady-state wait = vmcnt(6); first iter (no stores yet) = vmcnt(3);
//    last iter (no prefetch) = vmcnt(3); single-tile block would need vmcnt(0)
//    (handled, though GRID=768 < NTILE guarantees >=9 tiles/block here).
//  - Addressing identical to R4 (all verified): linear LDS stride 56,
//    source-side XOR swizzle col^il, conflict-free b128 phase-2 reads,
//    512B-aligned contiguous output runs.

constexpr int B    = 256;
constexpr int C    = 3;
constexpr int H    = 224;
constexpr int P    = 16;
constexpr int PHN  = 14;
constexpr int PWN  = 14;
constexpr int W4   = 56;                 // float4 per image row
constexpr int HALF = 8;                  // rows per half-slab
constexpr int NV   = C * HALF * W4;      // 1344 float4 per half-slab tile
constexpr int TPB  = 448;                // 7 waves
constexpr int ITERS = NV / TPB;          // 3, exact
constexpr int NTILE = B * PHN * 2;       // 7168 tiles
constexpr int GRID  = 768;               // 3 blocks/CU resident

typedef const __attribute__((address_space(1))) void g_void;
typedef __attribute__((address_space(3))) void l_void;

__global__ __launch_bounds__(TPB)
void patch_pipe_kernel(const float4* __restrict__ in, float4* __restrict__ out) {
    __shared__ float4 lds4[2][NV];       // 2 * 21504 B = 43008 B

    const int tid  = threadIdx.x;
    const int il   = tid / W4;           // 0..7
    const int col  = tid - il * W4;      // 0..55
    const int colg = col ^ il;           // source-side bank swizzle (involution)

    auto issue = [&](int t, int bufi) {
        int h   = t & 1;
        int blk = t >> 1;
        int ph  = blk % PHN;
        int b   = blk / PHN;
        const float4* s0 =
            in + ((size_t)(b * C) * H + ph * P + h * HALF + il) * W4 + colg;
        #pragma unroll
        for (int k = 0; k < ITERS; ++k)
            __builtin_amdgcn_global_load_lds((g_void*)(s0 + (size_t)k * H * W4),
                                             (l_void*)&lds4[bufi][k * TPB + tid],
                                             16, 0, 0);
    };

    const int t0 = blockIdx.x;
    issue(t0, 0);                        // prologue prefetch
    int cur = 0;

    for (int t = t0; t < NTILE; t += GRID) {
        const bool has_next = (t + GRID < NTILE);
        if (has_next) issue(t + GRID, cur ^ 1);

        // drain exactly the current tile's 3 loads (uniform branches)
        if (t == t0) {
            if (has_next) asm volatile("s_waitcnt vmcnt(3)" ::: "memory");
            else          asm volatile("s_waitcnt vmcnt(0)" ::: "memory");
        } else {
            if (has_next) asm volatile("s_waitcnt vmcnt(6)" ::: "memory");
            else          asm volatile("s_waitcnt vmcnt(3)" ::: "memory");
        }
        __builtin_amdgcn_s_barrier();    // tile t fully in LDS (all waves)

        // ---- phase 2: LDS -> regs -> global stores ----
        float4 s[ITERS];
        #pragma unroll
        for (int k = 0; k < ITERS; ++k) {
            int v   = tid + k * TPB;
            int j4  = v & 3;
            int il2 = (v >> 2) & (HALF - 1);
            int g   = v >> 5;            // pw*C + c
            int c   = g % C;
            int pw  = g / C;
            s[k] = lds4[cur][(c * HALF + il2) * W4 + ((pw * 4 + j4) ^ il2)];
        }
        {
            int h   = t & 1;
            int blk = t >> 1;
            int ph  = blk % PHN;
            int b   = blk / PHN;
            const int obase =
                (b * (PHN * PWN) + ph * PWN) * 192 + h * (HALF * 4);
            #pragma unroll
            for (int k = 0; k < ITERS; ++k) {
                int v   = tid + k * TPB;
                int j4  = v & 3;
                int il2 = (v >> 2) & (HALF - 1);
                int g   = v >> 5;
                int c   = g % C;
                int pw  = g / C;
                out[obase + pw * 192 + c * 64 + il2 * 4 + j4] = s[k];
            }
        }
        __builtin_amdgcn_s_barrier();    // buf free before next prefetch overwrites
        cur ^= 1;
    }
}

extern "C" void kernel_launch(void* const* d_in, const int* in_sizes, int n_in,
                              void* d_out, int out_size, void* d_ws, size_t ws_size,
                              hipStream_t stream) {
    const float4* in  = (const float4*)d_in[0];
    float4*       out = (float4*)d_out;
    patch_pipe_kernel<<<GRID, TPB, 0, stream>>>(in, out);
}